// Round 16
// baseline (237.166 us; speedup 1.0000x reference)
//
#include <hip/hip_runtime.h>
#include <hip/hip_bf16.h>
#include <math.h>

#define L_DIM 4096
#define H_DIM 512
#define B_DIM 8
#define SEG 2048

typedef __attribute__((ext_vector_type(8))) short short8;
typedef __attribute__((ext_vector_type(4))) float floatx4;

__device__ __forceinline__ unsigned f2bf(float f) {
    unsigned x = __float_as_uint(f);
    return (x + 0x7fffu + ((x >> 16) & 1u)) >> 16;   // RNE, finite inputs only
}

// ---------------------------------------------------------------------------
// Stage 1 (MFMA): causal Toeplitz conv + D-skip + exact GELU.
// UNCHANGED from round-15 (passed, 127.7us, occ 74%, VGPR 28). T=4/window-4,
// 1024-thread blocks, c<16 residues, stride-512 window. Conv is confirmed
// parked at ~126us across 3 schedules x 2 occupancy points (LDS-pipe +
// conflict cycles ~72% of window at T=4; latency-bound at T=8).
// ---------------------------------------------------------------------------
__global__ __launch_bounds__(1024, 8) void conv_gelu_mfma(
    const float* __restrict__ u,    // (B,H,L) fp32
    const float* __restrict__ kk,   // (C=1,H,L) fp32
    const float* __restrict__ Dp,   // (H) fp32
    unsigned short* __restrict__ g, // (B,H,L) bf16 out (workspace)
    const float* __restrict__ W,    // (H,H) fp32
    unsigned short* __restrict__ Wb)// (H,H) bf16 frag-major (workspace tail), may be null
{
    __shared__ __align__(16) unsigned short kA[4144];
    __shared__ __align__(16) unsigned short kB[4144];
    __shared__ __align__(16) unsigned short us[8][2104];

    const int h   = blockIdx.x;
    const int Lb  = blockIdx.y << 11;        // l-chunk base (2048 per block)
    const int tid = threadIdx.x;
    const int lane = tid & 63;
    const int w   = tid >> 6;                // wave id 0..15
    const int i   = lane & 15;               // A-row / C-col index
    const int q   = lane >> 4;               // quad
    const int b   = i & 7;                   // batch   (C-col decode)
    const int s   = i >> 3;                  // l-tile  (C-col decode)

    // one-time W fp32 -> bf16 frag-major conversion (one row per h-block)
    if (Wb != nullptr && blockIdx.y == 0 && tid < H_DIM) {
        const float* wsrc = W + (size_t)h * H_DIM;
        const int c = tid;
        const int idx = (((h >> 4) * 64 + (c >> 3)) * 16 + (h & 15)) * 8 + (c & 7);
        Wb[idx] = (unsigned short)f2bf(wsrc[c]);
    }

    const float* kh = kk + (size_t)h * L_DIM;

    for (int p = tid; p < 4144; p += 1024) {
        int t1 = L_DIM + 15 - p;
        int t2 = L_DIM + 14 - p;
        float v1 = (t1 >= 0 && t1 < L_DIM) ? kh[t1] : 0.0f;
        float v2 = (t2 >= 0 && t2 < L_DIM) ? kh[t2] : 0.0f;
        kA[p] = (unsigned short)f2bf(v1);
        kB[p] = (unsigned short)f2bf(v2);
    }

    floatx4 acc[4];
    #pragma unroll
    for (int t = 0; t < 4; t++) acc[t] = (floatx4){0.f, 0.f, 0.f, 0.f};

    const char* kbase = (const char*)((i & 1) ? kA : kB);
    const int aconst = 2 * (L_DIM + ((i & 1) ? 15 : 14) - i + 8 * q);
    const int basew = Lb + 32 * w;           // l0(t) = basew + 512*t, t in [0,4)

    union AFrag { int x[4]; short8 v; };

    for (int seg = 0; seg < 2; seg++) {
        const int ms = seg * SEG;
        const int mstart = (seg == 0) ? -32 : SEG;
        const int segmax = ms + SEG - 32;
        if (seg == 1) {
            // max m0 any wave needs = basew_max + 512*3 = Lb + 2016
            if (Lb + 2016 < SEG) break;      // uniform per block
            __syncthreads();                 // protect us[] until seg-0 compute done
        }
        for (int e = tid * 4; e < 2096; e += 4096) {
            int m = ms - 32 + e;
            #pragma unroll
            for (int bb = 0; bb < 8; bb++) {
                float4 v = make_float4(0.f, 0.f, 0.f, 0.f);
                if (m >= 0 && m < L_DIM)
                    v = *(const float4*)(u + ((size_t)bb * H_DIM + h) * L_DIM + m);
                unsigned lo = f2bf(v.x) | (f2bf(v.y) << 16);
                unsigned hi = f2bf(v.z) | (f2bf(v.w) << 16);
                *(uint2*)&us[bb][e] = make_uint2(lo, hi);
            }
        }
        __syncthreads();

        const char* bbase = (const char*)&us[b][0] + 2 * (32 - ms + 16 * s + 8 * q);
        const char* ab = kbase + aconst;     // A-frag address at dd = 0

        for (int c = 0; c < 16; c++) {       // 16 residues: m0-step 512 == t-stride
            const int c32 = 32 * c;
            const int rel = basew - c32;
            // m0(j) = rel - 512*j must lie in [mstart, segmax]
            const int j_hi = (rel - mstart) >> 9;            // floor div
            int j_lo = (rel - segmax + 511) >> 9;            // ceil div
            if (j_lo < -3) j_lo = -3;                        // t<=3 bound
            if (j_hi < j_lo) continue;
            const int n = j_hi - j_lo + 1;

            AFrag Wd[4];
            // preload slots d=1..3: sigma = j_hi + d, dd = c32 + 512*sigma <= 4096
            #pragma unroll
            for (int d = 1; d < 4; d++) {
                const int dd = c32 + (j_hi + d) * 512;
                if (dd >= 0) {
                    const int* ap = (const int*)(ab - 2 * dd);
                    Wd[d].x[0] = ap[0]; Wd[d].x[1] = ap[1];
                    Wd[d].x[2] = ap[2]; Wd[d].x[3] = ap[3];
                } else {
                    Wd[d].x[0] = 0; Wd[d].x[1] = 0; Wd[d].x[2] = 0; Wd[d].x[3] = 0;
                }
            }

            const char* aab = ab - 2 * c32 - 1024 * j_hi;    // +1024*jj -> frag at j=j_hi-jj
            const char* bb0 = bbase + 2 * (rel - 512 * j_hi);// +1024*jj -> B at m0(j)

            for (int jb = 0; jb < n; jb += 4) {
                #pragma unroll
                for (int k = 0; k < 4; k++) {
                    const int jj = jb + k;
                    if (jj < n) {
                        const int dd0 = c32 + (j_hi - jj) * 512;
                        AFrag nf;
                        if (dd0 >= 0) {
                            const int* ap = (const int*)(aab + 1024 * jj);
                            nf.x[0] = ap[0]; nf.x[1] = ap[1];
                            nf.x[2] = ap[2]; nf.x[3] = ap[3];
                        } else {
                            // non-causal diagonal: zero frag -> MFMA adds 0
                            nf.x[0] = 0; nf.x[1] = 0; nf.x[2] = 0; nf.x[3] = 0;
                        }
                        Wd[(4 - k) & 3] = nf;                // slot (-jj)&3, static
                        short8 bf = *(const short8*)(bb0 + 1024 * jj);
                        #pragma unroll
                        for (int t = 0; t < 4; t++)
                            acc[t] = __builtin_amdgcn_mfma_f32_16x16x32_bf16(
                                Wd[(t - k) & 3].v, bf, acc[t], 0, 0, 0);
                    }
                }
            }
        }
    }

    const float Dh = Dp[h];
    #pragma unroll
    for (int t = 0; t < 4; t++) {
        const int l0 = Lb + 32 * w + 512 * t;
        const int lb2 = l0 + 16 * s + 4 * q;          // C/D: row = 4q + r, col = (b,s)
        const size_t off = ((size_t)b * H_DIM + h) * L_DIM + lb2;
        float4 uv = *(const float4*)(u + off);
        float y0 = acc[t][0] + uv.x * Dh;
        float y1 = acc[t][1] + uv.y * Dh;
        float y2 = acc[t][2] + uv.z * Dh;
        float y3 = acc[t][3] + uv.w * Dh;
        const float c = 0.70710678118654752f;
        float g0 = 0.5f * y0 * (1.0f + erff(y0 * c));
        float g1 = 0.5f * y1 * (1.0f + erff(y1 * c));
        float g2 = 0.5f * y2 * (1.0f + erff(y2 * c));
        float g3 = 0.5f * y3 * (1.0f + erff(y3 * c));
        unsigned lo = f2bf(g0) | (f2bf(g1) << 16);
        unsigned hi = f2bf(g2) | (f2bf(g3) << 16);
        *(uint2*)(g + off) = make_uint2(lo, hi);
    }
}

// ---------------------------------------------------------------------------
// Stage 2 (MFMA v5, REVERT): out[b,d,l] = sum_c W[d,c]*g[b,c,l] + bias[d].
// Cross-round ledger: round-12's split-diagnostic hard-bounded every v5
// dispatch < 79.7us (never entered top-5), and its total reconciles
// (160 + ~84 + gaps = 246.7). Rounds 13/15 totals reconcile only if
// v7 ~ 100-106us: the round-13 l-halving was a ~25us hidden regression,
// masked by the simultaneous conv-unsplit (-35us). Revert to the round-9
// v5 verbatim: 256l x 256d, 1024 threads (4 wl x 4 wd of 64l x 64d),
// gs2-only double buffer (2 x 40KB), frag-major W straight from global.
// ---------------------------------------------------------------------------
template <bool PREW>
__global__ __launch_bounds__(1024, 4) void pointwise_mfma(
    const unsigned short* __restrict__ g,  // (B,H,L) bf16 (workspace)
    const unsigned short* __restrict__ Wb, // (H,H) bf16 frag-major if PREW
    const float* __restrict__ W,           // (H,H) fp32 row-major [d][c]
    const float* __restrict__ bias,        // (H) fp32
    float* __restrict__ out)               // (B,H,L) fp32
{
    __shared__ __align__(16) unsigned gs2[2][256 * 40];     // 2 x 40960 B

    const int tid = threadIdx.x;
    const int d0 = blockIdx.x * 256;
    const int l0 = blockIdx.y * 256;
    const int bz = blockIdx.z;
    const int w  = tid >> 6;
    const int lane = tid & 63;
    const int n  = lane & 15;      // MFMA row/col lane index
    const int q  = lane >> 4;      // quad
    const int wl = w >> 2;         // l-quarter 0..3 (64 l each)
    const int wd = w & 3;          // d-quarter 0..3 (64 d each)

    const int p   = tid & 31;      // c-pair column for g staging
    const int grp = tid >> 5;      // l-8-group 0..31 for g staging

    floatx4 acc[4][4];
    #pragma unroll
    for (int mt = 0; mt < 4; mt++)
        #pragma unroll
        for (int nt = 0; nt < 4; nt++) acc[mt][nt] = (floatx4){0.f, 0.f, 0.f, 0.f};

    const unsigned short* gbase = g + ((size_t)bz * H_DIM + 2 * p) * L_DIM + l0 + 8 * grp;

    uint4 ga, gb;   // staged g rows (live across compute for prefetch overlap)

    auto LOAD = [&](int c0) {
        const unsigned short* gp = gbase + (size_t)c0 * L_DIM;
        ga = *(const uint4*)gp;           // row c0+2p,   8 l
        gb = *(const uint4*)(gp + L_DIM); // row c0+2p+1, 8 l
    };
    auto WRITE = [&](int bf) {
        const unsigned* ua = (const unsigned*)&ga;
        const unsigned* ub = (const unsigned*)&gb;
        #pragma unroll
        for (int e = 0; e < 4; e++) {
            unsigned w0 = (ua[e] & 0xFFFFu) | (ub[e] << 16);        // l even
            unsigned w1 = (ua[e] >> 16) | (ub[e] & 0xFFFF0000u);    // l odd
            const int lrow = 8 * grp + 2 * e;
            gs2[bf][lrow * 40 + p] = w0;
            gs2[bf][(lrow + 1) * 40 + p] = w1;
        }
    };

    LOAD(0);
    WRITE(0);
    __syncthreads();

    for (int it = 0; it < 8; it++) {
        const int cur = it & 1;
        const int c0 = 64 * it;
        if (it < 7) LOAD(64 * (it + 1));         // issue next tile's loads early

        // ---- compute on gs2[cur]: 2 K-steps of 32; 4 mt x 4 nt MFMAs each
        #pragma unroll
        for (int ks = 0; ks < 2; ks++) {
            short8 bw[4];                         // W B-frags, straight from global
            #pragma unroll
            for (int nt = 0; nt < 4; nt++) {
                if (PREW) {
                    // frag-major: lane n reads 16B at n*16B -> contiguous 256B
                    const unsigned short* wp = Wb +
                        ((((size_t)(d0 >> 4) + 4 * wd + nt) * 64 + (c0 >> 3) + 4 * ks + q) * 16 + n) * 8;
                    bw[nt] = *(const short8*)wp;
                } else {
                    const int d = d0 + 64 * wd + 16 * nt + n;
                    const float* wp = W + (size_t)d * H_DIM + c0 + 32 * ks + 8 * q;
                    float4 f0 = ((const float4*)wp)[0];
                    float4 f1 = ((const float4*)wp)[1];
                    union { unsigned u[4]; short8 v; } pk;
                    pk.u[0] = f2bf(f0.x) | (f2bf(f0.y) << 16);
                    pk.u[1] = f2bf(f0.z) | (f2bf(f0.w) << 16);
                    pk.u[2] = f2bf(f1.x) | (f2bf(f1.y) << 16);
                    pk.u[3] = f2bf(f1.z) | (f2bf(f1.w) << 16);
                    bw[nt] = pk.v;
                }
            }
            #pragma unroll
            for (int mt = 0; mt < 4; mt++) {
                union { uint4 u4; short8 v; } af;
                af.u4 = *(const uint4*)&gs2[cur][(64 * wl + 16 * mt + n) * 40 + 16 * ks + 4 * q];
                #pragma unroll
                for (int nt = 0; nt < 4; nt++)
                    acc[mt][nt] = __builtin_amdgcn_mfma_f32_16x16x32_bf16(af.v, bw[nt], acc[mt][nt], 0, 0, 0);
            }
        }

        if (it < 7) WRITE(cur ^ 1);              // land prefetched tile in other buffer
        __syncthreads();                         // single barrier per iteration
    }

    // ---- epilogue: bias + coalesced float4 stores (4 consecutive l per lane)
    #pragma unroll
    for (int nt = 0; nt < 4; nt++) {
        const int d = d0 + 64 * wd + 16 * nt + n;
        const float bb = bias[d];
        float* obase = out + ((size_t)bz * H_DIM + d) * L_DIM + l0 + 64 * wl + 4 * q;
        #pragma unroll
        for (int mt = 0; mt < 4; mt++) {
            float4 r = make_float4(acc[mt][nt][0] + bb, acc[mt][nt][1] + bb,
                                   acc[mt][nt][2] + bb, acc[mt][nt][3] + bb);
            *(float4*)(obase + 16 * mt) = r;
        }
    }
}

extern "C" void kernel_launch(void* const* d_in, const int* in_sizes, int n_in,
                              void* d_out, int out_size, void* d_ws, size_t ws_size,
                              hipStream_t stream) {
    const float* u    = (const float*)d_in[0]; // (B,H,L)
    const float* k    = (const float*)d_in[1]; // (C,H,L) C=1
    const float* D    = (const float*)d_in[2]; // (C,H)
    const float* W    = (const float*)d_in[3]; // (H,C*H)
    const float* bias = (const float*)d_in[4]; // (H)
    float* out = (float*)d_out;
    unsigned short* g = (unsigned short*)d_ws;  // (B,H,L) bf16 intermediate, 32 MiB

    const size_t g_bytes = (size_t)B_DIM * H_DIM * L_DIM * sizeof(unsigned short); // 32 MiB
    const size_t w_bytes = (size_t)H_DIM * H_DIM * sizeof(unsigned short);         // 512 KiB
    const bool prew = ws_size >= g_bytes + w_bytes;
    unsigned short* Wb = prew ? (unsigned short*)((char*)d_ws + g_bytes) : nullptr;

    conv_gelu_mfma<<<dim3(H_DIM, L_DIM / 2048), 1024, 0, stream>>>(u, k, D, g, W, Wb);
    if (prew)
        pointwise_mfma<true><<<dim3(H_DIM / 256, L_DIM / 256, B_DIM), 1024, 0, stream>>>(g, Wb, W, bias, out);
    else
        pointwise_mfma<false><<<dim3(H_DIM / 256, L_DIM / 256, B_DIM), 1024, 0, stream>>>(g, nullptr, W, bias, out);
}

// Round 17
// 226.773 us; speedup vs baseline: 1.0458x; 1.0458x over previous
//
#include <hip/hip_runtime.h>
#include <hip/hip_bf16.h>
#include <math.h>

#define L_DIM 4096
#define H_DIM 512
#define B_DIM 8
#define SEG 2048

typedef __attribute__((ext_vector_type(8))) short short8;
typedef __attribute__((ext_vector_type(4))) float floatx4;

__device__ __forceinline__ unsigned f2bf(float f) {
    unsigned x = __float_as_uint(f);
    return (x + 0x7fffu + ((x >> 16) & 1u)) >> 16;   // RNE, finite inputs only
}

// ---------------------------------------------------------------------------
// Stage 1 (MFMA): causal Toeplitz conv + D-skip + exact GELU.
// Round-24: round-15 kernel (best-measured, 127.7us within the 233.1 total)
// + explicit kA/kB placement. SQ_LDS_BANK_CONFLICT = 2.07e7 ~ 34us/CU of
// conv's runtime; B-frag reads are provably 2-way optimal, so the conflicts
// come from the A-frag b32 reads: each parity group spans ~20 words at
// multiplicity 2 (free), but the CROSS-parity overlap depends on kA<->kB
// relative placement (was compiler-chosen, 2072 words = 24 mod 32 -> ~12
// banks at 3-4-way). Merged buffer puts kB at 4192 shorts = 2096 words =
// 16 mod 32, minimizing the overlap (8 banks). Addressing otherwise
// bit-identical; bounds: kA idx <= 4142 < 4144, kB idx in [4192, 8334).
// ---------------------------------------------------------------------------
__global__ __launch_bounds__(1024, 8) void conv_gelu_mfma(
    const float* __restrict__ u,    // (B,H,L) fp32
    const float* __restrict__ kk,   // (C=1,H,L) fp32
    const float* __restrict__ Dp,   // (H) fp32
    unsigned short* __restrict__ g, // (B,H,L) bf16 out (workspace)
    const float* __restrict__ W,    // (H,H) fp32
    unsigned short* __restrict__ Wb)// (H,H) bf16 frag-major (workspace tail), may be null
{
    __shared__ __align__(16) unsigned short kbuf[8336];   // kA @0, kB @4192 (banks 16 apart)
    __shared__ __align__(16) unsigned short us[8][2104];

    unsigned short* kA = kbuf;
    unsigned short* kB = kbuf + 4192;

    const int h   = blockIdx.x;
    const int Lb  = blockIdx.y << 11;        // l-chunk base (2048 per block)
    const int tid = threadIdx.x;
    const int lane = tid & 63;
    const int w   = tid >> 6;                // wave id 0..15
    const int i   = lane & 15;               // A-row / C-col index
    const int q   = lane >> 4;               // quad
    const int b   = i & 7;                   // batch   (C-col decode)
    const int s   = i >> 3;                  // l-tile  (C-col decode)

    // one-time W fp32 -> bf16 frag-major conversion (one row per h-block)
    if (Wb != nullptr && blockIdx.y == 0 && tid < H_DIM) {
        const float* wsrc = W + (size_t)h * H_DIM;
        const int c = tid;
        const int idx = (((h >> 4) * 64 + (c >> 3)) * 16 + (h & 15)) * 8 + (c & 7);
        Wb[idx] = (unsigned short)f2bf(wsrc[c]);
    }

    const float* kh = kk + (size_t)h * L_DIM;

    for (int p = tid; p < 4144; p += 1024) {
        int t1 = L_DIM + 15 - p;
        int t2 = L_DIM + 14 - p;
        float v1 = (t1 >= 0 && t1 < L_DIM) ? kh[t1] : 0.0f;
        float v2 = (t2 >= 0 && t2 < L_DIM) ? kh[t2] : 0.0f;
        kA[p] = (unsigned short)f2bf(v1);
        kB[p] = (unsigned short)f2bf(v2);
    }

    floatx4 acc[4];
    #pragma unroll
    for (int t = 0; t < 4; t++) acc[t] = (floatx4){0.f, 0.f, 0.f, 0.f};

    const char* kbase = (const char*)((i & 1) ? kA : kB);
    const int aconst = 2 * (L_DIM + ((i & 1) ? 15 : 14) - i + 8 * q);
    const int basew = Lb + 32 * w;           // l0(t) = basew + 512*t, t in [0,4)

    union AFrag { int x[4]; short8 v; };

    for (int seg = 0; seg < 2; seg++) {
        const int ms = seg * SEG;
        const int mstart = (seg == 0) ? -32 : SEG;
        const int segmax = ms + SEG - 32;
        if (seg == 1) {
            // max m0 any wave needs = basew_max + 512*3 = Lb + 2016
            if (Lb + 2016 < SEG) break;      // uniform per block
            __syncthreads();                 // protect us[] until seg-0 compute done
        }
        for (int e = tid * 4; e < 2096; e += 4096) {
            int m = ms - 32 + e;
            #pragma unroll
            for (int bb = 0; bb < 8; bb++) {
                float4 v = make_float4(0.f, 0.f, 0.f, 0.f);
                if (m >= 0 && m < L_DIM)
                    v = *(const float4*)(u + ((size_t)bb * H_DIM + h) * L_DIM + m);
                unsigned lo = f2bf(v.x) | (f2bf(v.y) << 16);
                unsigned hi = f2bf(v.z) | (f2bf(v.w) << 16);
                *(uint2*)&us[bb][e] = make_uint2(lo, hi);
            }
        }
        __syncthreads();

        const char* bbase = (const char*)&us[b][0] + 2 * (32 - ms + 16 * s + 8 * q);
        const char* ab = kbase + aconst;     // A-frag address at dd = 0

        for (int c = 0; c < 16; c++) {       // 16 residues: m0-step 512 == t-stride
            const int c32 = 32 * c;
            const int rel = basew - c32;
            // m0(j) = rel - 512*j must lie in [mstart, segmax]
            const int j_hi = (rel - mstart) >> 9;            // floor div
            int j_lo = (rel - segmax + 511) >> 9;            // ceil div
            if (j_lo < -3) j_lo = -3;                        // t<=3 bound
            if (j_hi < j_lo) continue;
            const int n = j_hi - j_lo + 1;

            AFrag Wd[4];
            // preload slots d=1..3: sigma = j_hi + d, dd = c32 + 512*sigma <= 4096
            #pragma unroll
            for (int d = 1; d < 4; d++) {
                const int dd = c32 + (j_hi + d) * 512;
                if (dd >= 0) {
                    const int* ap = (const int*)(ab - 2 * dd);
                    Wd[d].x[0] = ap[0]; Wd[d].x[1] = ap[1];
                    Wd[d].x[2] = ap[2]; Wd[d].x[3] = ap[3];
                } else {
                    Wd[d].x[0] = 0; Wd[d].x[1] = 0; Wd[d].x[2] = 0; Wd[d].x[3] = 0;
                }
            }

            const char* aab = ab - 2 * c32 - 1024 * j_hi;    // +1024*jj -> frag at j=j_hi-jj
            const char* bb0 = bbase + 2 * (rel - 512 * j_hi);// +1024*jj -> B at m0(j)

            for (int jb = 0; jb < n; jb += 4) {
                #pragma unroll
                for (int k = 0; k < 4; k++) {
                    const int jj = jb + k;
                    if (jj < n) {
                        const int dd0 = c32 + (j_hi - jj) * 512;
                        AFrag nf;
                        if (dd0 >= 0) {
                            const int* ap = (const int*)(aab + 1024 * jj);
                            nf.x[0] = ap[0]; nf.x[1] = ap[1];
                            nf.x[2] = ap[2]; nf.x[3] = ap[3];
                        } else {
                            // non-causal diagonal: zero frag -> MFMA adds 0
                            nf.x[0] = 0; nf.x[1] = 0; nf.x[2] = 0; nf.x[3] = 0;
                        }
                        Wd[(4 - k) & 3] = nf;                // slot (-jj)&3, static
                        short8 bf = *(const short8*)(bb0 + 1024 * jj);
                        #pragma unroll
                        for (int t = 0; t < 4; t++)
                            acc[t] = __builtin_amdgcn_mfma_f32_16x16x32_bf16(
                                Wd[(t - k) & 3].v, bf, acc[t], 0, 0, 0);
                    }
                }
            }
        }
    }

    const float Dh = Dp[h];
    #pragma unroll
    for (int t = 0; t < 4; t++) {
        const int l0 = Lb + 32 * w + 512 * t;
        const int lb2 = l0 + 16 * s + 4 * q;          // C/D: row = 4q + r, col = (b,s)
        const size_t off = ((size_t)b * H_DIM + h) * L_DIM + lb2;
        float4 uv = *(const float4*)(u + off);
        float y0 = acc[t][0] + uv.x * Dh;
        float y1 = acc[t][1] + uv.y * Dh;
        float y2 = acc[t][2] + uv.z * Dh;
        float y3 = acc[t][3] + uv.w * Dh;
        const float c = 0.70710678118654752f;
        float g0 = 0.5f * y0 * (1.0f + erff(y0 * c));
        float g1 = 0.5f * y1 * (1.0f + erff(y1 * c));
        float g2 = 0.5f * y2 * (1.0f + erff(y2 * c));
        float g3 = 0.5f * y3 * (1.0f + erff(y3 * c));
        unsigned lo = f2bf(g0) | (f2bf(g1) << 16);
        unsigned hi = f2bf(g2) | (f2bf(g3) << 16);
        *(uint2*)(g + off) = make_uint2(lo, hi);
    }
}

// ---------------------------------------------------------------------------
// Stage 2 (MFMA v7, round-15 verbatim -- part of the best-measured 233.1us
// total): 128l x 256d tile, 512 threads (2 wl x 4 wd of 64l x 64d),
// 2 x 20KB gs2 dbuf -> 2 blocks/CU, single-barrier pipeline, frag-major W
// straight from global. v5-vs-v7 A/B across rounds 15/16: equal within
// noise; keep the one from the best-measured total.
// ---------------------------------------------------------------------------
template <bool PREW>
__global__ __launch_bounds__(512, 4) void pointwise_mfma(
    const unsigned short* __restrict__ g,  // (B,H,L) bf16 (workspace)
    const unsigned short* __restrict__ Wb, // (H,H) bf16 frag-major if PREW
    const float* __restrict__ W,           // (H,H) fp32 row-major [d][c]
    const float* __restrict__ bias,        // (H) fp32
    float* __restrict__ out)               // (B,H,L) fp32
{
    __shared__ __align__(16) unsigned gs2[2][128 * 40];     // 2 x 20480 B

    const int tid = threadIdx.x;
    const int d0 = blockIdx.x * 256;
    const int l0 = blockIdx.y * 128;
    const int bz = blockIdx.z;
    const int w  = tid >> 6;
    const int lane = tid & 63;
    const int n  = lane & 15;      // MFMA row/col lane index
    const int q  = lane >> 4;      // quad
    const int wl = w >> 2;         // l-half 0..1 (64 l each)
    const int wd = w & 3;          // d-quarter 0..3 (64 d each)

    const int p   = tid & 31;      // c-pair column for g staging
    const int grp = tid >> 5;      // l-8-group 0..15 for g staging

    floatx4 acc[4][4];
    #pragma unroll
    for (int mt = 0; mt < 4; mt++)
        #pragma unroll
        for (int nt = 0; nt < 4; nt++) acc[mt][nt] = (floatx4){0.f, 0.f, 0.f, 0.f};

    const unsigned short* gbase = g + ((size_t)bz * H_DIM + 2 * p) * L_DIM + l0 + 8 * grp;

    uint4 ga, gb;   // staged g rows (live across compute for prefetch overlap)

    auto LOAD = [&](int c0) {
        const unsigned short* gp = gbase + (size_t)c0 * L_DIM;
        ga = *(const uint4*)gp;           // row c0+2p,   8 l
        gb = *(const uint4*)(gp + L_DIM); // row c0+2p+1, 8 l
    };
    auto WRITE = [&](int bf) {
        const unsigned* ua = (const unsigned*)&ga;
        const unsigned* ub = (const unsigned*)&gb;
        #pragma unroll
        for (int e = 0; e < 4; e++) {
            unsigned w0 = (ua[e] & 0xFFFFu) | (ub[e] << 16);        // l even
            unsigned w1 = (ua[e] >> 16) | (ub[e] & 0xFFFF0000u);    // l odd
            const int lrow = 8 * grp + 2 * e;
            gs2[bf][lrow * 40 + p] = w0;
            gs2[bf][(lrow + 1) * 40 + p] = w1;
        }
    };

    LOAD(0);
    WRITE(0);
    __syncthreads();

    for (int it = 0; it < 8; it++) {
        const int cur = it & 1;
        const int c0 = 64 * it;
        if (it < 7) LOAD(64 * (it + 1));         // issue next tile's loads early

        // ---- compute on gs2[cur]: 2 K-steps of 32; 4 mt x 4 nt MFMAs each
        #pragma unroll
        for (int ks = 0; ks < 2; ks++) {
            short8 bw[4];                         // W B-frags, straight from global
            #pragma unroll
            for (int nt = 0; nt < 4; nt++) {
                if (PREW) {
                    // frag-major: lane n reads 16B at n*16B -> contiguous 256B
                    const unsigned short* wp = Wb +
                        ((((size_t)(d0 >> 4) + 4 * wd + nt) * 64 + (c0 >> 3) + 4 * ks + q) * 16 + n) * 8;
                    bw[nt] = *(const short8*)wp;
                } else {
                    const int d = d0 + 64 * wd + 16 * nt + n;
                    const float* wp = W + (size_t)d * H_DIM + c0 + 32 * ks + 8 * q;
                    float4 f0 = ((const float4*)wp)[0];
                    float4 f1 = ((const float4*)wp)[1];
                    union { unsigned u[4]; short8 v; } pk;
                    pk.u[0] = f2bf(f0.x) | (f2bf(f0.y) << 16);
                    pk.u[1] = f2bf(f0.z) | (f2bf(f0.w) << 16);
                    pk.u[2] = f2bf(f1.x) | (f2bf(f1.y) << 16);
                    pk.u[3] = f2bf(f1.z) | (f2bf(f1.w) << 16);
                    bw[nt] = pk.v;
                }
            }
            #pragma unroll
            for (int mt = 0; mt < 4; mt++) {
                union { uint4 u4; short8 v; } af;
                af.u4 = *(const uint4*)&gs2[cur][(64 * wl + 16 * mt + n) * 40 + 16 * ks + 4 * q];
                #pragma unroll
                for (int nt = 0; nt < 4; nt++)
                    acc[mt][nt] = __builtin_amdgcn_mfma_f32_16x16x32_bf16(af.v, bw[nt], acc[mt][nt], 0, 0, 0);
            }
        }

        if (it < 7) WRITE(cur ^ 1);              // land prefetched tile in other buffer
        __syncthreads();                         // single barrier per iteration
    }

    // ---- epilogue: bias + coalesced float4 stores (4 consecutive l per lane)
    #pragma unroll
    for (int nt = 0; nt < 4; nt++) {
        const int d = d0 + 64 * wd + 16 * nt + n;
        const float bb = bias[d];
        float* obase = out + ((size_t)bz * H_DIM + d) * L_DIM + l0 + 64 * wl + 4 * q;
        #pragma unroll
        for (int mt = 0; mt < 4; mt++) {
            float4 r = make_float4(acc[mt][nt][0] + bb, acc[mt][nt][1] + bb,
                                   acc[mt][nt][2] + bb, acc[mt][nt][3] + bb);
            *(float4*)(obase + 16 * mt) = r;
        }
    }
}

extern "C" void kernel_launch(void* const* d_in, const int* in_sizes, int n_in,
                              void* d_out, int out_size, void* d_ws, size_t ws_size,
                              hipStream_t stream) {
    const float* u    = (const float*)d_in[0]; // (B,H,L)
    const float* k    = (const float*)d_in[1]; // (C,H,L) C=1
    const float* D    = (const float*)d_in[2]; // (C,H)
    const float* W    = (const float*)d_in[3]; // (H,C*H)
    const float* bias = (const float*)d_in[4]; // (H)
    float* out = (float*)d_out;
    unsigned short* g = (unsigned short*)d_ws;  // (B,H,L) bf16 intermediate, 32 MiB

    const size_t g_bytes = (size_t)B_DIM * H_DIM * L_DIM * sizeof(unsigned short); // 32 MiB
    const size_t w_bytes = (size_t)H_DIM * H_DIM * sizeof(unsigned short);         // 512 KiB
    const bool prew = ws_size >= g_bytes + w_bytes;
    unsigned short* Wb = prew ? (unsigned short*)((char*)d_ws + g_bytes) : nullptr;

    conv_gelu_mfma<<<dim3(H_DIM, L_DIM / 2048), 1024, 0, stream>>>(u, k, D, g, W, Wb);
    if (prew)
        pointwise_mfma<true><<<dim3(H_DIM / 256, L_DIM / 128, B_DIM), 512, 0, stream>>>(g, Wb, W, bias, out);
    else
        pointwise_mfma<false><<<dim3(H_DIM / 256, L_DIM / 128, B_DIM), 512, 0, stream>>>(g, nullptr, W, bias, out);
}